// Round 1
// 1116.635 us; speedup vs baseline: 1.0140x; 1.0140x over previous
//
#include <hip/hip_runtime.h>

// LowRankINRLayer: out[b,n,o] = relu( sum_r ( sum_d x[b,n,d]*v[b,r,d] ) * W[o,r] )
// B=16, N=8192, DI=512, DO=512, R=32, all fp32.
// Memory floor: x 256MB + out 256MB + v/W ~1.1MB @ ~6.3 TB/s => ~82 us.
// fp32 VALU compute: 8.6 GFLOP @ 157 TF => ~55 us. Memory-bound if clean.
//
// Round-2 diagnosis: previous version kept 64 fp32 accumulators/thread
// (2 rows x 32 ranks) -> compiler allocated only 64 VGPRs and spilled the
// accumulators to scratch. Counters: FETCH 1.8GB (6.9x ideal), WRITE 546MB
// (2.1x), VALUBusy 12.9% -> 87% stall on scratch traffic, 847 us.
//
// This version: rank-split. thread = (rl in [0,32), h in {0,1}, p in [0,4)).
//   Each thread: rows {rl, rl+32}, ranks [16h, 16h+16), d-slice p*4+16k.
//   => 2x16 = 32 accumulators. Peak live regs ~100 < 128 cap -> no spill.
//   x loads: 4-lane groups read 64B contiguous; consecutive k hits the same
//   128B line next iteration (L1). v loads: 2 lines/wave-instr (broadcast).
//   Butterfly over p (xor 1,2), p==0 lanes write xv to LDS (stride 36 floats,
//   16B aligned, 2-way conflict on the 16 active lanes = free).
// Phase 2 unchanged: thread t holds W rows {2t,2t+1} in VGPRs (accs are dead
//   by then), loops 64 rows via broadcast ds_read_b128, float2 stores ->
//   512B contiguous per wave.

#define B_  16
#define N_  8192
#define DI_ 512
#define DO_ 512
#define R_  32

#define ROWS   64     // rows per block
#define XV_LD  36     // padded LDS row stride (floats): 144B, 16B aligned

__global__ __launch_bounds__(256, 4) void lowrank_fused(
    const float* __restrict__ x, const float* __restrict__ v,
    const float* __restrict__ W, float* __restrict__ out)
{
    __shared__ float xv_s[ROWS * XV_LD];   // 9216 B

    const int t  = threadIdx.x;
    const int p  = t & 3;                  // d-part 0..3 (elems p*4 + 16k)
    const int h  = (t >> 2) & 1;           // rank half: ranks [16h, 16h+16)
    const int rl = t >> 3;                 // row-local 0..31 (owns rl, rl+32)
    const int bidx = blockIdx.x;
    const int b = bidx >> 7;               // 128 blocks per batch (8192/64)
    const int row_base = (bidx & 127) << 6;

    const size_t rbase = (size_t)b * N_ + row_base;
    const float* __restrict__ xr0 = x + (rbase + rl) * DI_ + p * 4;
    const float* __restrict__ xr1 = xr0 + 32 * DI_;
    const float* __restrict__ vb  = v + (size_t)b * (R_ * DI_)
                                      + (size_t)(h * 16) * DI_ + p * 4;

    float acc0[16], acc1[16];
#pragma unroll
    for (int j = 0; j < 16; ++j) { acc0[j] = 0.f; acc1[j] = 0.f; }

    // Phase 1: partial dots over this thread's 128 d-elements (32 float4 steps)
#pragma unroll 2
    for (int k = 0; k < 32; ++k) {
        const float4 xa = *(const float4*)(xr0 + 16 * k);
        const float4 xb = *(const float4*)(xr1 + 16 * k);
#pragma unroll
        for (int j = 0; j < 16; ++j) {
            const float4 vv = *(const float4*)(vb + j * DI_ + 16 * k);
            acc0[j] = fmaf(xa.x, vv.x, acc0[j]);
            acc0[j] = fmaf(xa.y, vv.y, acc0[j]);
            acc0[j] = fmaf(xa.z, vv.z, acc0[j]);
            acc0[j] = fmaf(xa.w, vv.w, acc0[j]);
            acc1[j] = fmaf(xb.x, vv.x, acc1[j]);
            acc1[j] = fmaf(xb.y, vv.y, acc1[j]);
            acc1[j] = fmaf(xb.z, vv.z, acc1[j]);
            acc1[j] = fmaf(xb.w, vv.w, acc1[j]);
        }
    }

    // Butterfly reduce across the 4 d-part lanes (xor 1, 2)
#pragma unroll
    for (int j = 0; j < 16; ++j) {
        acc0[j] += __shfl_xor(acc0[j], 1, 64);
        acc1[j] += __shfl_xor(acc1[j], 1, 64);
    }
#pragma unroll
    for (int j = 0; j < 16; ++j) {
        acc0[j] += __shfl_xor(acc0[j], 2, 64);
        acc1[j] += __shfl_xor(acc1[j], 2, 64);
    }

    if (p == 0) {
        float* d0 = &xv_s[rl * XV_LD + h * 16];
        float* d1 = &xv_s[(rl + 32) * XV_LD + h * 16];
#pragma unroll
        for (int j = 0; j < 4; ++j) {
            float4 a = make_float4(acc0[4*j], acc0[4*j+1], acc0[4*j+2], acc0[4*j+3]);
            float4 c = make_float4(acc1[4*j], acc1[4*j+1], acc1[4*j+2], acc1[4*j+3]);
            *(float4*)(d0 + 4*j) = a;
            *(float4*)(d1 + 4*j) = c;
        }
    }
    __syncthreads();

    // Phase 2: thread t -> output columns {2t, 2t+1} for all 64 rows.
    float4 W0[8], W1[8];
    {
        const float* Wp = W + (size_t)(2 * t) * R_;
#pragma unroll
        for (int j = 0; j < 8; ++j) {
            W0[j] = *(const float4*)(Wp + 4*j);
            W1[j] = *(const float4*)(Wp + R_ + 4*j);
        }
    }

    float* __restrict__ obase = out + rbase * DO_ + 2 * t;
#pragma unroll 2
    for (int row = 0; row < ROWS; ++row) {
        const float* xvr = &xv_s[row * XV_LD];
        float s0 = 0.f, s1 = 0.f;
#pragma unroll
        for (int j = 0; j < 8; ++j) {
            const float4 xf = *(const float4*)(xvr + 4*j);
            s0 = fmaf(xf.x, W0[j].x, s0);
            s0 = fmaf(xf.y, W0[j].y, s0);
            s0 = fmaf(xf.z, W0[j].z, s0);
            s0 = fmaf(xf.w, W0[j].w, s0);
            s1 = fmaf(xf.x, W1[j].x, s1);
            s1 = fmaf(xf.y, W1[j].y, s1);
            s1 = fmaf(xf.z, W1[j].z, s1);
            s1 = fmaf(xf.w, W1[j].w, s1);
        }
        float2 res;
        res.x = fmaxf(s0, 0.f);
        res.y = fmaxf(s1, 0.f);
        *(float2*)(obase + (size_t)row * DO_) = res;
    }
}

extern "C" void kernel_launch(void* const* d_in, const int* in_sizes, int n_in,
                              void* d_out, int out_size, void* d_ws, size_t ws_size,
                              hipStream_t stream) {
    const float* x  = (const float*)d_in[0];
    const float* v  = (const float*)d_in[1];
    const float* W  = (const float*)d_in[2];
    float* out      = (float*)d_out;

    const int threads = 256;
    const int blocks  = (B_ * N_) / ROWS;   // 2048 blocks
    lowrank_fused<<<blocks, threads, 0, stream>>>(x, v, W, out);
}

// Round 2
// 1047.844 us; speedup vs baseline: 1.0805x; 1.0656x over previous
//
#include <hip/hip_runtime.h>

// LowRankINRLayer: out[b,n,o] = relu( sum_r ( sum_d x[b,n,d]*v[b,r,d] ) * W[o,r] )
// B=16, N=8192, DI=512, DO=512, R=32, all fp32.
// Memory floor: x 256MB + out 256MB + v/W ~1.1MB @ ~6.3 TB/s => ~82 us.
// fp32 VALU compute: 8.6 GFLOP @ 157 TF => ~55 us.
//
// Round-2 post-mortem: rank-split (32 accs) changed NOTHING (identical
// counters: VGPR 64, FETCH 1.87GB, VALUBusy 13%, 827us). Spill theory dead.
// What both rounds shared: each of the 32 rl-groups per block re-reads the
// block's v slice -> 2MB/block x 2048 = 4GB of v traffic. The 268MB x stream
// flushes v out of L1/L2, so ~1.6GB of those misses reach the fabric:
// 268MB(x) + 1.6GB(v) == 1.87GB FETCH observed. v refetch IS the bottleneck.
//
// This version: stage v in LDS, 4 chunks of [32 ranks][128 d] = 16KB.
//   Each chunk loaded once per block (coalesced 512B/row/wave, L2-resident
//   source), consumed 32x from LDS instead of from thrashed L2/L3.
//   LDS v-read: 4 p-lanes x 64B contiguous, 2-way h-alias (free, m136),
//   8-way rl broadcast -> conflict-free.
//   LDS total 16KB + 9KB = 25KB -> occupancy still 4 blocks/CU.
// Phase 2 unchanged: thread t holds W rows {2t,2t+1}; broadcast ds_read_b128
//   of xv; float2 stores -> 512B contiguous per wave.

#define B_  16
#define N_  8192
#define DI_ 512
#define DO_ 512
#define R_  32

#define ROWS   64     // rows per block
#define XV_LD  36     // padded LDS row stride (floats): 144B, 16B aligned
#define CD     128    // v-chunk depth (d elements per chunk)
#define NC     (DI_ / CD)   // 4 chunks

__global__ __launch_bounds__(256, 4) void lowrank_fused(
    const float* __restrict__ x, const float* __restrict__ v,
    const float* __restrict__ W, float* __restrict__ out)
{
    __shared__ float v_s[R_ * CD];          // 16384 B
    __shared__ float xv_s[ROWS * XV_LD];    // 9216 B

    const int t  = threadIdx.x;
    const int p  = t & 3;                  // d-part 0..3 (elems p*4 + 16k)
    const int h  = (t >> 2) & 1;           // rank half: ranks [16h, 16h+16)
    const int rl = t >> 3;                 // row-local 0..31 (owns rl, rl+32)
    const int bidx = blockIdx.x;
    const int b = bidx >> 7;               // 128 blocks per batch (8192/64)
    const int row_base = (bidx & 127) << 6;

    const size_t rbase = (size_t)b * N_ + row_base;
    const float* __restrict__ xr0 = x + (rbase + rl) * DI_ + p * 4;
    const float* __restrict__ xr1 = xr0 + 32 * DI_;

    // v staging: thread t loads rows {t>>5 + 8j}, cols (t&31)*4 .. +3 of chunk
    const int sr = t >> 5;                 // 0..7
    const int sc = (t & 31) * 4;           // 0..124
    const float* __restrict__ vsrc = v + (size_t)b * (R_ * DI_)
                                       + (size_t)sr * DI_ + sc;

    float acc0[16], acc1[16];
#pragma unroll
    for (int j = 0; j < 16; ++j) { acc0[j] = 0.f; acc1[j] = 0.f; }

    const float* __restrict__ vrow = &v_s[(h * 16) * CD + p * 4];

    for (int c = 0; c < NC; ++c) {
        // Issue staging loads before the sync so they overlap other waves'
        // tail compute on the previous chunk.
        float4 st[4];
#pragma unroll
        for (int j = 0; j < 4; ++j)
            st[j] = *(const float4*)(vsrc + (size_t)(8 * j) * DI_ + c * CD);

        __syncthreads();   // previous chunk fully consumed
#pragma unroll
        for (int j = 0; j < 4; ++j)
            *(float4*)(&v_s[(sr + 8 * j) * CD + sc]) = st[j];
        __syncthreads();   // chunk visible to all

        // Phase 1 over this chunk: 8 k-steps of 16 floats each
#pragma unroll
        for (int kk = 0; kk < 8; ++kk) {
            const int k = 8 * c + kk;
            const float4 xa = *(const float4*)(xr0 + 16 * k);
            const float4 xb = *(const float4*)(xr1 + 16 * k);
#pragma unroll
            for (int j = 0; j < 16; ++j) {
                const float4 vv = *(const float4*)(vrow + j * CD + 16 * kk);
                acc0[j] = fmaf(xa.x, vv.x, acc0[j]);
                acc0[j] = fmaf(xa.y, vv.y, acc0[j]);
                acc0[j] = fmaf(xa.z, vv.z, acc0[j]);
                acc0[j] = fmaf(xa.w, vv.w, acc0[j]);
                acc1[j] = fmaf(xb.x, vv.x, acc1[j]);
                acc1[j] = fmaf(xb.y, vv.y, acc1[j]);
                acc1[j] = fmaf(xb.z, vv.z, acc1[j]);
                acc1[j] = fmaf(xb.w, vv.w, acc1[j]);
            }
        }
    }

    // Butterfly reduce across the 4 d-part lanes (xor 1, 2)
#pragma unroll
    for (int j = 0; j < 16; ++j) {
        acc0[j] += __shfl_xor(acc0[j], 1, 64);
        acc1[j] += __shfl_xor(acc1[j], 1, 64);
    }
#pragma unroll
    for (int j = 0; j < 16; ++j) {
        acc0[j] += __shfl_xor(acc0[j], 2, 64);
        acc1[j] += __shfl_xor(acc1[j], 2, 64);
    }

    if (p == 0) {
        float* d0 = &xv_s[rl * XV_LD + h * 16];
        float* d1 = &xv_s[(rl + 32) * XV_LD + h * 16];
#pragma unroll
        for (int j = 0; j < 4; ++j) {
            float4 a = make_float4(acc0[4*j], acc0[4*j+1], acc0[4*j+2], acc0[4*j+3]);
            float4 c = make_float4(acc1[4*j], acc1[4*j+1], acc1[4*j+2], acc1[4*j+3]);
            *(float4*)(d0 + 4*j) = a;
            *(float4*)(d1 + 4*j) = c;
        }
    }
    __syncthreads();

    // Phase 2: thread t -> output columns {2t, 2t+1} for all 64 rows.
    float4 W0[8], W1[8];
    {
        const float* Wp = W + (size_t)(2 * t) * R_;
#pragma unroll
        for (int j = 0; j < 8; ++j) {
            W0[j] = *(const float4*)(Wp + 4*j);
            W1[j] = *(const float4*)(Wp + R_ + 4*j);
        }
    }

    float* __restrict__ obase = out + rbase * DO_ + 2 * t;
#pragma unroll 2
    for (int row = 0; row < ROWS; ++row) {
        const float* xvr = &xv_s[row * XV_LD];
        float s0 = 0.f, s1 = 0.f;
#pragma unroll
        for (int j = 0; j < 8; ++j) {
            const float4 xf = *(const float4*)(xvr + 4*j);
            s0 = fmaf(xf.x, W0[j].x, s0);
            s0 = fmaf(xf.y, W0[j].y, s0);
            s0 = fmaf(xf.z, W0[j].z, s0);
            s0 = fmaf(xf.w, W0[j].w, s0);
            s1 = fmaf(xf.x, W1[j].x, s1);
            s1 = fmaf(xf.y, W1[j].y, s1);
            s1 = fmaf(xf.z, W1[j].z, s1);
            s1 = fmaf(xf.w, W1[j].w, s1);
        }
        float2 res;
        res.x = fmaxf(s0, 0.f);
        res.y = fmaxf(s1, 0.f);
        *(float2*)(obase + (size_t)row * DO_) = res;
    }
}

extern "C" void kernel_launch(void* const* d_in, const int* in_sizes, int n_in,
                              void* d_out, int out_size, void* d_ws, size_t ws_size,
                              hipStream_t stream) {
    const float* x  = (const float*)d_in[0];
    const float* v  = (const float*)d_in[1];
    const float* W  = (const float*)d_in[2];
    float* out      = (float*)d_out;

    const int threads = 256;
    const int blocks  = (B_ * N_) / ROWS;   // 2048 blocks
    lowrank_fused<<<blocks, threads, 0, stream>>>(x, v, W, out);
}

// Round 3
// 527.478 us; speedup vs baseline: 2.1465x; 1.9865x over previous
//
#include <hip/hip_runtime.h>

// LowRankINRLayer: out[b,n,o] = relu( sum_r ( sum_d x[b,n,d]*v[b,r,d] ) * W[o,r] )
// B=16, N=8192, DI=512, DO=512, R=32, all fp32.
// Memory floor: x 256MB + out 256MB + v/W ~1.1MB @ ~6.3 TB/s => ~82 us.
// fp32 VALU compute: 8.6 GFLOP @ 157 TF => ~55 us.
//
// Round-3 diagnosis: FETCH stuck at 1.87GB across THREE structurally
// different phase-1 variants; VGPR_Count stuck at 64. Phase 2 holds
// W0[8]+W1[8] = 64 floats/thread -- impossible to keep resident in a
// 64-VGPR allocation. Under __launch_bounds__(256,4) the compiler pinned
// 64 regs and either spills W/accs to scratch or rematerializes W loads
// inside the 64-row loop: ~16KB/thread re-read -> 8.6GB L1/L2-level W
// traffic, whose L2-miss residue (~1.5GB) is exactly the constant FETCH
// excess. WRITE excess (260-460MB) = scratch stores. VALUBusy 13.8% =
// waves starved on scratch/remat latency. Register famine, self-inflicted.
//
// This version: identical algorithm, __launch_bounds__(256, 2) -> 256-VGPR
// budget. Compiler allocates the true live set (~130-170), W stays in
// registers, scratch traffic disappears. Occupancy drops to ~3 waves/EU,
// which is fine: waves that actually run beat waves that wait on scratch.
//
// Phase 1: rank-split. thread = (rl in [0,32), h in {0,1}, p in [0,4)).
//   rows {rl, rl+32}, ranks [16h,16h+16), d-slice p*4+16k. 32 accs.
//   v staged in LDS in 4 chunks of [32 ranks][128 d] = 16KB (loaded once
//   per block, coalesced; consumed 32x from LDS).
// Phase 2: thread t -> columns {2t,2t+1}; W rows in VGPRs; broadcast
//   ds_read_b128 of xv; float2 stores -> 512B contiguous per wave.

#define B_  16
#define N_  8192
#define DI_ 512
#define DO_ 512
#define R_  32

#define ROWS   64     // rows per block
#define XV_LD  36     // padded LDS row stride (floats): 144B, 16B aligned
#define CD     128    // v-chunk depth (d elements per chunk)
#define NC     (DI_ / CD)   // 4 chunks

__global__ __launch_bounds__(256, 2) void lowrank_fused(
    const float* __restrict__ x, const float* __restrict__ v,
    const float* __restrict__ W, float* __restrict__ out)
{
    __shared__ float v_s[R_ * CD];          // 16384 B
    __shared__ float xv_s[ROWS * XV_LD];    // 9216 B

    const int t  = threadIdx.x;
    const int p  = t & 3;                  // d-part 0..3 (elems p*4 + 16k)
    const int h  = (t >> 2) & 1;           // rank half: ranks [16h, 16h+16)
    const int rl = t >> 3;                 // row-local 0..31 (owns rl, rl+32)
    const int bidx = blockIdx.x;
    const int b = bidx >> 7;               // 128 blocks per batch (8192/64)
    const int row_base = (bidx & 127) << 6;

    const size_t rbase = (size_t)b * N_ + row_base;
    const float* __restrict__ xr0 = x + (rbase + rl) * DI_ + p * 4;
    const float* __restrict__ xr1 = xr0 + 32 * DI_;

    // v staging: thread t loads rows {t>>5 + 8j}, cols (t&31)*4 .. +3 of chunk
    const int sr = t >> 5;                 // 0..7
    const int sc = (t & 31) * 4;           // 0..124
    const float* __restrict__ vsrc = v + (size_t)b * (R_ * DI_)
                                       + (size_t)sr * DI_ + sc;

    float acc0[16], acc1[16];
#pragma unroll
    for (int j = 0; j < 16; ++j) { acc0[j] = 0.f; acc1[j] = 0.f; }

    const float* __restrict__ vrow = &v_s[(h * 16) * CD + p * 4];

    for (int c = 0; c < NC; ++c) {
        // Issue staging loads before the sync so they overlap other waves'
        // tail compute on the previous chunk.
        float4 st[4];
#pragma unroll
        for (int j = 0; j < 4; ++j)
            st[j] = *(const float4*)(vsrc + (size_t)(8 * j) * DI_ + c * CD);

        __syncthreads();   // previous chunk fully consumed
#pragma unroll
        for (int j = 0; j < 4; ++j)
            *(float4*)(&v_s[(sr + 8 * j) * CD + sc]) = st[j];
        __syncthreads();   // chunk visible to all

        // Phase 1 over this chunk: 8 k-steps of 16 floats each
#pragma unroll
        for (int kk = 0; kk < 8; ++kk) {
            const int k = 8 * c + kk;
            const float4 xa = *(const float4*)(xr0 + 16 * k);
            const float4 xb = *(const float4*)(xr1 + 16 * k);
#pragma unroll
            for (int j = 0; j < 16; ++j) {
                const float4 vv = *(const float4*)(vrow + j * CD + 16 * kk);
                acc0[j] = fmaf(xa.x, vv.x, acc0[j]);
                acc0[j] = fmaf(xa.y, vv.y, acc0[j]);
                acc0[j] = fmaf(xa.z, vv.z, acc0[j]);
                acc0[j] = fmaf(xa.w, vv.w, acc0[j]);
                acc1[j] = fmaf(xb.x, vv.x, acc1[j]);
                acc1[j] = fmaf(xb.y, vv.y, acc1[j]);
                acc1[j] = fmaf(xb.z, vv.z, acc1[j]);
                acc1[j] = fmaf(xb.w, vv.w, acc1[j]);
            }
        }
    }

    // Butterfly reduce across the 4 d-part lanes (xor 1, 2)
#pragma unroll
    for (int j = 0; j < 16; ++j) {
        acc0[j] += __shfl_xor(acc0[j], 1, 64);
        acc1[j] += __shfl_xor(acc1[j], 1, 64);
    }
#pragma unroll
    for (int j = 0; j < 16; ++j) {
        acc0[j] += __shfl_xor(acc0[j], 2, 64);
        acc1[j] += __shfl_xor(acc1[j], 2, 64);
    }

    if (p == 0) {
        float* d0 = &xv_s[rl * XV_LD + h * 16];
        float* d1 = &xv_s[(rl + 32) * XV_LD + h * 16];
#pragma unroll
        for (int j = 0; j < 4; ++j) {
            float4 a = make_float4(acc0[4*j], acc0[4*j+1], acc0[4*j+2], acc0[4*j+3]);
            float4 c = make_float4(acc1[4*j], acc1[4*j+1], acc1[4*j+2], acc1[4*j+3]);
            *(float4*)(d0 + 4*j) = a;
            *(float4*)(d1 + 4*j) = c;
        }
    }
    __syncthreads();

    // Phase 2: thread t -> output columns {2t, 2t+1} for all 64 rows.
    float4 W0[8], W1[8];
    {
        const float* Wp = W + (size_t)(2 * t) * R_;
#pragma unroll
        for (int j = 0; j < 8; ++j) {
            W0[j] = *(const float4*)(Wp + 4*j);
            W1[j] = *(const float4*)(Wp + R_ + 4*j);
        }
    }

    float* __restrict__ obase = out + rbase * DO_ + 2 * t;
#pragma unroll 2
    for (int row = 0; row < ROWS; ++row) {
        const float* xvr = &xv_s[row * XV_LD];
        float s0 = 0.f, s1 = 0.f;
#pragma unroll
        for (int j = 0; j < 8; ++j) {
            const float4 xf = *(const float4*)(xvr + 4*j);
            s0 = fmaf(xf.x, W0[j].x, s0);
            s0 = fmaf(xf.y, W0[j].y, s0);
            s0 = fmaf(xf.z, W0[j].z, s0);
            s0 = fmaf(xf.w, W0[j].w, s0);
            s1 = fmaf(xf.x, W1[j].x, s1);
            s1 = fmaf(xf.y, W1[j].y, s1);
            s1 = fmaf(xf.z, W1[j].z, s1);
            s1 = fmaf(xf.w, W1[j].w, s1);
        }
        float2 res;
        res.x = fmaxf(s0, 0.f);
        res.y = fmaxf(s1, 0.f);
        *(float2*)(obase + (size_t)row * DO_) = res;
    }
}

extern "C" void kernel_launch(void* const* d_in, const int* in_sizes, int n_in,
                              void* d_out, int out_size, void* d_ws, size_t ws_size,
                              hipStream_t stream) {
    const float* x  = (const float*)d_in[0];
    const float* v  = (const float*)d_in[1];
    const float* W  = (const float*)d_in[2];
    float* out      = (float*)d_out;

    const int threads = 256;
    const int blocks  = (B_ * N_) / ROWS;   // 2048 blocks
    lowrank_fused<<<blocks, threads, 0, stream>>>(x, v, W, out);
}

// Round 4
// 488.400 us; speedup vs baseline: 2.3182x; 1.0800x over previous
//
#include <hip/hip_runtime.h>

// LowRankINRLayer: out[b,n,o] = relu( sum_r ( sum_d x[b,n,d]*v[b,r,d] ) * W[o,r] )
// B=16, N=8192, DI=512, DO=512, R=32, all fp32.
// Memory floor: ~153MB fetch (L3 assists x) + 268MB write @6.3TB/s => ~67 us.
//
// Round-4 post-mortem: launch_bounds(256,2) fixed the register famine
// (VGPR 64->84, FETCH 1.87GB->153MB, 768->235us). Remaining budget:
// VALU 110us (2x the 55us fp32-FMA floor), LDS v-reads ~82us + 27us bank
// conflicts (16.8M cyc: h=0/h=1 16B slots alias on banks 0-15). VALU+LDS
// co-critical -> incremental fixes cap at ~140us.
//
// This version: phase 1 -> MFMA (v_mfma_f32_16x16x32_bf16) with 2-term
// bf16 split for fp32 accuracy: x=hi+lo, v=hi+lo, D = hi*hi + hi*lo + lo*hi
// (lo*lo ~2^-32, dropped). End-to-end error ~1e-3 << 0.5 tolerance.
//   Wave w owns rows [16w,16w+16): A-frag lane(row=l&15, k=(l>>4)*8+j) read
//   straight from global x (x read once per block; 16 lines/instr, L1 ok).
//   B-frag = v^T: lane(k=(l>>4)*8+j, col=l&15) -> v[rank=nt*16+l&15][k],
//   L2-resident (64KB/batch shared by 128 blocks). No v LDS staging at all:
//   kills the 82us LDS stream + 27us conflicts + 55us of phase-1 VALU FMA.
//   D layout (m89-verified): col=l&15, row=(l>>4)*4+reg -> scatter to xv_s
//   in the exact layout phase 2 already reads (stride 36; 2-way alias free).
// Phase 2: byte-identical to round 3 (proven 27us VALU, coalesced stores).

typedef __attribute__((ext_vector_type(8))) short short8;
typedef __attribute__((ext_vector_type(4))) float f32x4;

#define B_  16
#define N_  8192
#define DI_ 512
#define DO_ 512
#define R_  32

#define ROWS   64     // rows per block
#define XV_LD  36     // padded LDS row stride (floats): 144B, 16B aligned

__device__ __forceinline__ unsigned short bf16_rne(float f) {
    unsigned bits = __float_as_uint(f);
    return (unsigned short)((bits + 0x7FFFu + ((bits >> 16) & 1u)) >> 16);
}

__device__ __forceinline__ void split8(const float4 a, const float4 b,
                                       short8& hi, short8& lo) {
    const float f[8] = {a.x, a.y, a.z, a.w, b.x, b.y, b.z, b.w};
#pragma unroll
    for (int j = 0; j < 8; ++j) {
        const unsigned short h = bf16_rne(f[j]);
        const float hf = __uint_as_float((unsigned)h << 16);
        hi[j] = (short)h;
        lo[j] = (short)bf16_rne(f[j] - hf);
    }
}

__global__ __launch_bounds__(256, 2) void lowrank_fused(
    const float* __restrict__ x, const float* __restrict__ v,
    const float* __restrict__ W, float* __restrict__ out)
{
    __shared__ float xv_s[ROWS * XV_LD];   // 9216 B (only LDS in the kernel)

    const int t  = threadIdx.x;
    const int w  = t >> 6;                 // wave 0..3 -> rows [16w, 16w+16)
    const int l  = t & 63;
    const int lr = l & 15;                 // fragment row (A) / col (B,D)
    const int lk = l >> 4;                 // k-group 0..3
    const int bidx = blockIdx.x;
    const int b = bidx >> 7;               // 128 blocks per batch (8192/64)
    const int row_base = (bidx & 127) << 6;
    const size_t rbase = (size_t)b * N_ + row_base;

    // Phase 1: xv[64][32] = x[64][512] @ v[b]^T via MFMA, split-bf16.
    const float* __restrict__ xA = x + (rbase + 16 * w + lr) * DI_ + lk * 8;
    const float* __restrict__ vB = v + ((size_t)b * R_ + lr) * DI_ + lk * 8;

    f32x4 acc0 = {0.f, 0.f, 0.f, 0.f};     // rank tile 0 (ranks 0-15)
    f32x4 acc1 = {0.f, 0.f, 0.f, 0.f};     // rank tile 1 (ranks 16-31)

#pragma unroll 2
    for (int ks = 0; ks < 16; ++ks) {
        const float4 a0 = *(const float4*)(xA + 32 * ks);
        const float4 a1 = *(const float4*)(xA + 32 * ks + 4);
        const float4 b0 = *(const float4*)(vB + 32 * ks);
        const float4 b1 = *(const float4*)(vB + 32 * ks + 4);
        const float4 c0 = *(const float4*)(vB + 16 * DI_ + 32 * ks);
        const float4 c1 = *(const float4*)(vB + 16 * DI_ + 32 * ks + 4);

        short8 ahi, alo, bhi, blo, chi, clo;
        split8(a0, a1, ahi, alo);
        split8(b0, b1, bhi, blo);
        split8(c0, c1, chi, clo);

        acc0 = __builtin_amdgcn_mfma_f32_16x16x32_bf16(ahi, bhi, acc0, 0, 0, 0);
        acc1 = __builtin_amdgcn_mfma_f32_16x16x32_bf16(ahi, chi, acc1, 0, 0, 0);
        acc0 = __builtin_amdgcn_mfma_f32_16x16x32_bf16(ahi, blo, acc0, 0, 0, 0);
        acc1 = __builtin_amdgcn_mfma_f32_16x16x32_bf16(ahi, clo, acc1, 0, 0, 0);
        acc0 = __builtin_amdgcn_mfma_f32_16x16x32_bf16(alo, bhi, acc0, 0, 0, 0);
        acc1 = __builtin_amdgcn_mfma_f32_16x16x32_bf16(alo, chi, acc1, 0, 0, 0);
    }

    // D-layout scatter: lane holds xv[16w + 4*lk + r][nt*16 + lr], r=0..3.
    // Bank pattern per instr: (16*lk + 4r + 16nt + lr)%32 -> 2-way alias (free).
    {
        float* d = &xv_s[(16 * w + 4 * lk) * XV_LD + lr];
#pragma unroll
        for (int r = 0; r < 4; ++r) {
            d[r * XV_LD]      = acc0[r];
            d[r * XV_LD + 16] = acc1[r];
        }
    }
    __syncthreads();

    // Phase 2 (unchanged): thread t -> output columns {2t, 2t+1} for 64 rows.
    float4 W0[8], W1[8];
    {
        const float* Wp = W + (size_t)(2 * t) * R_;
#pragma unroll
        for (int j = 0; j < 8; ++j) {
            W0[j] = *(const float4*)(Wp + 4*j);
            W1[j] = *(const float4*)(Wp + R_ + 4*j);
        }
    }

    float* __restrict__ obase = out + rbase * DO_ + 2 * t;
#pragma unroll 2
    for (int row = 0; row < ROWS; ++row) {
        const float* xvr = &xv_s[row * XV_LD];
        float s0 = 0.f, s1 = 0.f;
#pragma unroll
        for (int j = 0; j < 8; ++j) {
            const float4 xf = *(const float4*)(xvr + 4*j);
            s0 = fmaf(xf.x, W0[j].x, s0);
            s0 = fmaf(xf.y, W0[j].y, s0);
            s0 = fmaf(xf.z, W0[j].z, s0);
            s0 = fmaf(xf.w, W0[j].w, s0);
            s1 = fmaf(xf.x, W1[j].x, s1);
            s1 = fmaf(xf.y, W1[j].y, s1);
            s1 = fmaf(xf.z, W1[j].z, s1);
            s1 = fmaf(xf.w, W1[j].w, s1);
        }
        float2 res;
        res.x = fmaxf(s0, 0.f);
        res.y = fmaxf(s1, 0.f);
        *(float2*)(obase + (size_t)row * DO_) = res;
    }
}

extern "C" void kernel_launch(void* const* d_in, const int* in_sizes, int n_in,
                              void* d_out, int out_size, void* d_ws, size_t ws_size,
                              hipStream_t stream) {
    const float* x  = (const float*)d_in[0];
    const float* v  = (const float*)d_in[1];
    const float* W  = (const float*)d_in[2];
    float* out      = (float*)d_out;

    const int threads = 256;
    const int blocks  = (B_ * N_) / ROWS;   // 2048 blocks
    lowrank_fused<<<blocks, threads, 0, stream>>>(x, v, W, out);
}